// Round 7
// baseline (362.648 us; speedup 1.0000x reference)
//
#include <hip/hip_runtime.h>

// BaseEncoder: x[B,F] fp32 -> out[B,F,32] fp32
//   out[...,0]   = (x < 0) ? 1 : 0
//   out[...,1+d] = bit (30-d) of bitcast(x)
//
// R9 DIAGNOSTIC: R7 (best, 262.6us) with the store phase repeated 4x.
//
// Rationale: five structural variants span only 262-283us and my kernel has
// NEVER appeared in the top-5 counter rows -- the harness's 1 GiB poison
// fills (~167us) occupy all five slots, so every estimate of the kernel's
// own time/BW is inference. Repeating the (idempotent) store pass 4x lifts
// the kernel's dispatch above the fills so rocprof reports ITS dur_us,
// FETCH_SIZE, WRITE_SIZE, OccupancyPercent, VALUBusy.
//   - Same values stored to same addresses each rep: output bit-identical.
//   - asm memory clobber between reps: no cross-rep dead-store elimination.
//   - #pragma unroll 1: reps stay sequential.
// Pre-committed readout:
//   A) diag ~360-400us, WRITE~1GiB, FETCH small, ~2.9 TB/s -> store path
//      genuinely slow; the row says why (occupancy / VALU / fetch).
//   B) diag ~180-210us, ~6 TB/s -> kernel already at roofline; the ~95us
//      residual in totals is not the kernel -> ROOFLINE next round.
//   C) FETCH ~= WRITE ~= 1 GiB -> hidden read-modify-write; fix next round.

typedef float f32x4 __attribute__((ext_vector_type(4)));

constexpr int BLOCK = 256;
constexpr int GRID = 2048;                 // 8 blocks/CU on 256 CUs
constexpr int STEPS = 32;                  // quads per thread
constexpr int QUADS_PER_BLOCK = BLOCK * STEPS;       // 8192 quads = 128 KiB out
constexpr int ELEMS_PER_BLOCK = QUADS_PER_BLOCK / 8; // 1024 floats = 4 KiB in
constexpr int REPS = 4;                    // DIAGNOSTIC multiplier

__global__ __launch_bounds__(BLOCK) void be_diag4(
    const float* __restrict__ x, f32x4* __restrict__ out) {
  __shared__ float smem[ELEMS_PER_BLOCK];

  const int t = threadIdx.x;
  const int b = blockIdx.x;

  // Stage-in: one coalesced float4 per thread (4 KiB per block).
  const f32x4 v = *reinterpret_cast<const f32x4*>(x + b * ELEMS_PER_BLOCK + t * 4);
  *reinterpret_cast<f32x4*>(&smem[t * 4]) = v;
  __syncthreads();

  const int g = t >> 3;                    // element slot within a 32-wide row
  const int j0 = (t & 7) << 2;             // channel phase, thread-invariant
  const bool sign_lane = (j0 == 0);
  const int s0 = 31 - j0, s1 = 30 - j0, s2 = 29 - j0, s3 = 28 - j0;
  f32x4* const op = out + b * QUADS_PER_BLOCK + t;

#pragma unroll 1
  for (int rep = 0; rep < REPS; ++rep) {
#pragma unroll
    for (int k = 0; k < STEPS; ++k) {
      const float xv = smem[k * 32 + g];
      const unsigned r = __float_as_uint(xv);
      f32x4 o;
      // channel 0 is the exact sign channel (x<0), not the sign bit.
      o.x = sign_lane ? ((xv < 0.0f) ? 1.0f : 0.0f)
                      : (float)((r >> s0) & 1u);
      o.y = (float)((r >> s1) & 1u);
      o.z = (float)((r >> s2) & 1u);
      o.w = (float)((r >> s3) & 1u);
      op[k * BLOCK] = o;
    }
    asm volatile("" ::: "memory");         // stores of every rep stay live
  }
}

// Fallback for shapes that don't divide exactly (single-pass, plain stores).
__global__ __launch_bounds__(BLOCK) void be_gs_r9(
    const float* __restrict__ x, f32x4* __restrict__ out, int n_quads) {
  const int stride = GRID * BLOCK;
  int tid = blockIdx.x * BLOCK + threadIdx.x;
  const int j0 = (tid & 7) << 2;
  const bool sign_lane = (j0 == 0);

  for (int base = tid; base < n_quads; base += 4 * stride) {
    int idx[4];
    float xv[4];
#pragma unroll
    for (int k = 0; k < 4; ++k) {
      idx[k] = base + k * stride;
      xv[k] = (idx[k] < n_quads) ? x[idx[k] >> 3] : 0.0f;
    }
#pragma unroll
    for (int k = 0; k < 4; ++k) {
      if (idx[k] < n_quads) {
        unsigned r = __float_as_uint(xv[k]);
        f32x4 o;
        o.x = (float)((r >> (31 - j0)) & 1u);
        o.y = (float)((r >> (30 - j0)) & 1u);
        o.z = (float)((r >> (29 - j0)) & 1u);
        o.w = (float)((r >> (28 - j0)) & 1u);
        if (sign_lane) o.x = (xv[k] < 0.0f) ? 1.0f : 0.0f;
        out[idx[k]] = o;
      }
    }
  }
}

extern "C" void kernel_launch(void* const* d_in, const int* in_sizes, int n_in,
                              void* d_out, int out_size, void* d_ws, size_t ws_size,
                              hipStream_t stream) {
  const float* x = (const float*)d_in[0];
  f32x4* out = (f32x4*)d_out;
  int n_elems = in_sizes[0];               // 4096*512 = 2,097,152
  int n_quads = n_elems * 8;               // 16,777,216 = GRID * QUADS_PER_BLOCK
  if (n_quads == GRID * QUADS_PER_BLOCK) {
    be_diag4<<<GRID, BLOCK, 0, stream>>>(x, out);
  } else {
    be_gs_r9<<<GRID, BLOCK, 0, stream>>>(x, out, n_quads);
  }
}

// Round 8
// 273.715 us; speedup vs baseline: 1.3249x; 1.3249x over previous
//
#include <hip/hip_runtime.h>

// BaseEncoder: x[B,F] fp32 -> out[B,F,32] fp32
//   out[...,0]   = (x < 0) ? 1 : 0
//   out[...,1+d] = bit (30-d) of bitcast(x)   (bits 30..0; abs() only clears
//                  bit 31, so bits 30..0 of x equal bits 30..0 of |x|)
//
// R10: revert to R7 (best, 262.6us) after the R9 diagnostic.
//
// R9 findings (4x store-pass kernel, 362.6us): marginal store pass =
// (362.6-262.6)/3 = 33.4us for 268 MB -- at/below the 41.7us cold-pass
// roofline at the fill kernel's own 6.44 TB/s. Solving F+L+P=262.6,
// F+L+4P=362.6 gives fixed harness term F+L ~= 229us, matching the visible
// poison fills (1 GiB ~170us + 256 MiB ~42us) plus ~10us kernel prologue.
// => The store stream is already at the HBM write roofline; dur_us floor
// ~= 255us and R7 sits within ~3% (inside fill-speed noise, 165-182us
// across rounds). Earlier "kernel ~95us @ 2.9 TB/s" was an additive-model
// artifact. This source is R7 unchanged.
//
// Structure: block b owns contiguous output quads [b*8192,(b+1)*8192)
// (128 KiB); input x[b*1024 .. b*1024+1024) staged to LDS via one coalesced
// float4/thread; store stream = 32 plain dwordx4/thread fed by ds_read_b32
// 8-lane broadcasts (conflict-free), no vmcnt deps inside the stream.

typedef float f32x4 __attribute__((ext_vector_type(4)));

constexpr int BLOCK = 256;
constexpr int GRID = 2048;                 // 8 blocks/CU on 256 CUs
constexpr int STEPS = 32;                  // quads per thread
constexpr int QUADS_PER_BLOCK = BLOCK * STEPS;       // 8192 quads = 128 KiB out
constexpr int ELEMS_PER_BLOCK = QUADS_PER_BLOCK / 8; // 1024 floats = 4 KiB in

__global__ __launch_bounds__(BLOCK) void base_encoder_lds(
    const float* __restrict__ x, f32x4* __restrict__ out) {
  __shared__ float smem[ELEMS_PER_BLOCK];

  const int t = threadIdx.x;
  const int b = blockIdx.x;

  // Phase 1: coalesced stage-in. 1 KiB per wave-load, 4 KiB per block.
  const f32x4 v = *reinterpret_cast<const f32x4*>(x + b * ELEMS_PER_BLOCK + t * 4);
  *reinterpret_cast<f32x4*>(&smem[t * 4]) = v;
  __syncthreads();

  const int g = t >> 3;                    // element slot within a 32-wide row
  const int j0 = (t & 7) << 2;             // channel phase, thread-invariant
  const bool sign_lane = (j0 == 0);
  const int s0 = 31 - j0, s1 = 30 - j0, s2 = 29 - j0, s3 = 28 - j0;
  f32x4* const op = out + b * QUADS_PER_BLOCK + t;

  // Phase 2: store stream via plain cached stores (L2 write-combines full
  // 64B lines; FETCH stays ~input-only).
#pragma unroll
  for (int k = 0; k < STEPS; ++k) {
    const float xv = smem[k * 32 + g];
    const unsigned r = __float_as_uint(xv);
    f32x4 o;
    // channel 0 is the exact sign channel (x<0), not the sign bit:
    // keeps -0.0 / NaN semantics identical to the reference.
    o.x = sign_lane ? ((xv < 0.0f) ? 1.0f : 0.0f)
                    : (float)((r >> s0) & 1u);
    o.y = (float)((r >> s1) & 1u);
    o.z = (float)((r >> s2) & 1u);
    o.w = (float)((r >> s3) & 1u);
    op[k * BLOCK] = o;
  }
}

// Fallback for shapes that don't divide exactly.
__global__ __launch_bounds__(BLOCK) void base_encoder_gs(
    const float* __restrict__ x, f32x4* __restrict__ out, int n_quads) {
  const int stride = GRID * BLOCK;
  int tid = blockIdx.x * BLOCK + threadIdx.x;
  const int j0 = (tid & 7) << 2;
  const bool sign_lane = (j0 == 0);

  for (int base = tid; base < n_quads; base += 4 * stride) {
    int idx[4];
    float xv[4];
#pragma unroll
    for (int k = 0; k < 4; ++k) {
      idx[k] = base + k * stride;
      xv[k] = (idx[k] < n_quads) ? x[idx[k] >> 3] : 0.0f;
    }
#pragma unroll
    for (int k = 0; k < 4; ++k) {
      if (idx[k] < n_quads) {
        unsigned r = __float_as_uint(xv[k]);
        f32x4 o;
        o.x = (float)((r >> (31 - j0)) & 1u);
        o.y = (float)((r >> (30 - j0)) & 1u);
        o.z = (float)((r >> (29 - j0)) & 1u);
        o.w = (float)((r >> (28 - j0)) & 1u);
        if (sign_lane) o.x = (xv[k] < 0.0f) ? 1.0f : 0.0f;
        out[idx[k]] = o;
      }
    }
  }
}

extern "C" void kernel_launch(void* const* d_in, const int* in_sizes, int n_in,
                              void* d_out, int out_size, void* d_ws, size_t ws_size,
                              hipStream_t stream) {
  const float* x = (const float*)d_in[0];
  f32x4* out = (f32x4*)d_out;
  int n_elems = in_sizes[0];               // 4096*512 = 2,097,152
  int n_quads = n_elems * 8;               // 16,777,216 = GRID * QUADS_PER_BLOCK
  if (n_quads == GRID * QUADS_PER_BLOCK) {
    base_encoder_lds<<<GRID, BLOCK, 0, stream>>>(x, out);
  } else {
    base_encoder_gs<<<GRID, BLOCK, 0, stream>>>(x, out, n_quads);
  }
}